// Round 1
// baseline (13535.954 us; speedup 1.0000x reference)
//
#include <hip/hip_runtime.h>
#include <cstddef>

// ---------------------------------------------------------------------------
// DeepKoopmanSplit — fp32 baseline, fused per-MLP kernels.
// B=8192, M=64, H=256, LP=32, LR=96, L=128, CD=4.
// Rows per block TR=16; activations live in LDS transposed [k][r] (stride 17
// to spread banks); weights staged through an 8x256 LDS panel with register
// prefetch so global latency overlaps compute.
// ---------------------------------------------------------------------------

#define TR   16
#define NTHR 256

// ------------------------- encoder layer 1 (K=3 or 9) ----------------------
template<int KIN, int OFF>
__device__ __forceinline__ void enc_layer1(const float (*s_x)[12], float (*s_h)[TR + 1],
                                           const float* __restrict__ W,
                                           const float* __restrict__ bia, int tid)
{
    const int r = tid & 15, cgp = tid >> 4;          // 16 rows x 16 col-groups
    float xv[KIN];
#pragma unroll
    for (int t = 0; t < KIN; ++t) xv[t] = s_x[r][OFF + t];
#pragma unroll 4
    for (int j = 0; j < 16; ++j) {
        const int c = cgp * 16 + j;
        float acc = bia[c];
#pragma unroll
        for (int t = 0; t < KIN; ++t) acc += W[c * KIN + t] * xv[t];
        s_h[c][r] = fmaxf(acc, 0.f);
    }
    __syncthreads();
}

// ------------------- dense 256->256 + ReLU (the heavy layer) ---------------
// s_in / s_out transposed [k][r]. Per thread: 2 rows x 8 cols.
__device__ __forceinline__ void layer_dense256(const float (*s_in)[TR + 1], float (*s_out)[TR + 1],
                                               const float* __restrict__ W,
                                               const float* __restrict__ bia,
                                               float (*s_w)[256], int tid)
{
    const int cg = tid & 31, rg = tid >> 5;
    const int c0 = cg * 8, r0 = rg * 2;
    float acc[2][8];
#pragma unroll
    for (int i = 0; i < 2; ++i)
#pragma unroll
        for (int j = 0; j < 8; ++j) acc[i][j] = 0.f;

    const float* wrow = W + tid * 256;               // thread stages row c=tid
    float4 p0 = *(const float4*)(wrow);
    float4 p1 = *(const float4*)(wrow + 4);
#pragma unroll 1
    for (int kc = 0; kc < 32; ++kc) {
        __syncthreads();
        s_w[0][tid] = p0.x; s_w[1][tid] = p0.y; s_w[2][tid] = p0.z; s_w[3][tid] = p0.w;
        s_w[4][tid] = p1.x; s_w[5][tid] = p1.y; s_w[6][tid] = p1.z; s_w[7][tid] = p1.w;
        if (kc < 31) {
            p0 = *(const float4*)(wrow + (kc + 1) * 8);
            p1 = *(const float4*)(wrow + (kc + 1) * 8 + 4);
        }
        __syncthreads();
#pragma unroll
        for (int kk = 0; kk < 8; ++kk) {
            const int k = kc * 8 + kk;
            const float a0 = s_in[k][r0], a1 = s_in[k][r0 + 1];
            const float4 w0 = *(const float4*)&s_w[kk][c0];
            const float4 w1 = *(const float4*)&s_w[kk][c0 + 4];
            acc[0][0] += a0 * w0.x; acc[0][1] += a0 * w0.y; acc[0][2] += a0 * w0.z; acc[0][3] += a0 * w0.w;
            acc[0][4] += a0 * w1.x; acc[0][5] += a0 * w1.y; acc[0][6] += a0 * w1.z; acc[0][7] += a0 * w1.w;
            acc[1][0] += a1 * w0.x; acc[1][1] += a1 * w0.y; acc[1][2] += a1 * w0.z; acc[1][3] += a1 * w0.w;
            acc[1][4] += a1 * w1.x; acc[1][5] += a1 * w1.y; acc[1][6] += a1 * w1.z; acc[1][7] += a1 * w1.w;
        }
    }
#pragma unroll
    for (int j = 0; j < 8; ++j) {
        const float bv = bia[c0 + j];
        s_out[c0 + j][r0]     = fmaxf(acc[0][j] + bv, 0.f);
        s_out[c0 + j][r0 + 1] = fmaxf(acc[1][j] + bv, 0.f);
    }
}

// -------------------- encoder layer 3: 256 -> N3 (32 or 96) ----------------
template<int N3>
__device__ __forceinline__ void enc_layer3(const float (*s_in)[TR + 1], float* __restrict__ zbase,
                                           const float* __restrict__ W2,
                                           const float* __restrict__ b2,
                                           float (*s_w)[256], int tid)
{
    constexpr int CT = N3 / 32;
    constexpr int PR = (N3 * 8) / 256;               // 1 (pos) or 3 (rest)
    const int cg = tid & 31, rg = tid >> 5;
    const int r0 = rg * 2;
    float acc[2][CT];
#pragma unroll
    for (int i = 0; i < 2; ++i)
#pragma unroll
        for (int j = 0; j < CT; ++j) acc[i][j] = 0.f;

    float pr[PR];
#pragma unroll
    for (int u = 0; u < PR; ++u) {
        const int idx = u * 256 + tid;
        pr[u] = W2[(idx % N3) * 256 + (idx / N3)];
    }
#pragma unroll 1
    for (int kc = 0; kc < 32; ++kc) {
        __syncthreads();
#pragma unroll
        for (int u = 0; u < PR; ++u) {
            const int idx = u * 256 + tid;
            s_w[idx / N3][idx % N3] = pr[u];
        }
        if (kc < 31) {
#pragma unroll
            for (int u = 0; u < PR; ++u) {
                const int idx = u * 256 + tid;
                pr[u] = W2[(idx % N3) * 256 + (kc + 1) * 8 + (idx / N3)];
            }
        }
        __syncthreads();
#pragma unroll
        for (int kk = 0; kk < 8; ++kk) {
            const int k = kc * 8 + kk;
            const float a0 = s_in[k][r0], a1 = s_in[k][r0 + 1];
#pragma unroll
            for (int j = 0; j < CT; ++j) {
                const float w = s_w[kk][cg + 32 * j];
                acc[0][j] += a0 * w;
                acc[1][j] += a1 * w;
            }
        }
    }
#pragma unroll
    for (int j = 0; j < CT; ++j) {
        const int c = cg + 32 * j;
        const float bv = b2[c];
        zbase[(size_t)r0 * 128 + c]       = acc[0][j] + bv;
        zbase[(size_t)(r0 + 1) * 128 + c] = acc[1][j] + bv;
    }
}

// ----------------------------- encoder kernel ------------------------------
__global__ void __launch_bounds__(NTHR, 2)
enc_kernel(const float* __restrict__ xin, float* __restrict__ zout,
           const float* __restrict__ ep_w0, const float* __restrict__ ep_b0,
           const float* __restrict__ ep_w1, const float* __restrict__ ep_b1,
           const float* __restrict__ ep_w2, const float* __restrict__ ep_b2,
           const float* __restrict__ er_w0, const float* __restrict__ er_b0,
           const float* __restrict__ er_w1, const float* __restrict__ er_b1,
           const float* __restrict__ er_w2, const float* __restrict__ er_b2)
{
    __shared__ __align__(16) float s_x[TR][12];
    __shared__ __align__(16) float s_a[256][TR + 1];
    __shared__ __align__(16) float s_b[256][TR + 1];
    __shared__ __align__(16) float s_w[8][256];
    const int tid = threadIdx.x;
    const size_t row0 = (size_t)blockIdx.x * TR;

    for (int idx = tid; idx < TR * 12; idx += NTHR)
        ((float*)s_x)[idx] = xin[row0 * 12 + idx];
    __syncthreads();

    // pos net: 3 -> 256 -> 256 -> 32
    enc_layer1<3, 0>(s_x, s_a, ep_w0, ep_b0, tid);
    layer_dense256(s_a, s_b, ep_w1, ep_b1, s_w, tid);
    __syncthreads();
    enc_layer3<32>(s_b, zout + row0 * 128, ep_w2, ep_b2, s_w, tid);
    __syncthreads();
    // rest net: 9 -> 256 -> 256 -> 96
    enc_layer1<9, 3>(s_x, s_a, er_w0, er_b0, tid);
    layer_dense256(s_a, s_b, er_w1, er_b1, s_w, tid);
    __syncthreads();
    enc_layer3<96>(s_b, zout + row0 * 128 + 32, er_w2, er_b2, s_w, tid);
}

// ---------------- decoder layer 1: K=32 (pos) or 96 (rest) -----------------
template<int KLEN>
__device__ __forceinline__ void dec_layer1(const float* __restrict__ zin, size_t row0, int koff,
                                           const float* __restrict__ W,
                                           const float* __restrict__ bia,
                                           float (*s_zp)[TR + 1], float (*s_w)[256],
                                           float (*s_out)[TR + 1], int tid)
{
    constexpr int CH = KLEN / 8;
    const int cg = tid & 31, rg = tid >> 5;
    const int c0 = cg * 8, r0 = rg * 2;
    float acc[2][8];
#pragma unroll
    for (int i = 0; i < 2; ++i)
#pragma unroll
        for (int j = 0; j < 8; ++j) acc[i][j] = 0.f;

    const float* wrow = W + tid * KLEN;
    float4 p0 = *(const float4*)(wrow);
    float4 p1 = *(const float4*)(wrow + 4);
    const int zr = tid & 15, zkk = tid >> 4;          // staging ids (tid<128)
    float zv = 0.f;
    if (tid < 128) zv = zin[(row0 + zr) * 128 + koff + zkk];
#pragma unroll 1
    for (int kc = 0; kc < CH; ++kc) {
        __syncthreads();
        s_w[0][tid] = p0.x; s_w[1][tid] = p0.y; s_w[2][tid] = p0.z; s_w[3][tid] = p0.w;
        s_w[4][tid] = p1.x; s_w[5][tid] = p1.y; s_w[6][tid] = p1.z; s_w[7][tid] = p1.w;
        if (tid < 128) s_zp[zkk][zr] = zv;
        if (kc < CH - 1) {
            p0 = *(const float4*)(wrow + (kc + 1) * 8);
            p1 = *(const float4*)(wrow + (kc + 1) * 8 + 4);
            if (tid < 128) zv = zin[(row0 + zr) * 128 + koff + (kc + 1) * 8 + zkk];
        }
        __syncthreads();
#pragma unroll
        for (int kk = 0; kk < 8; ++kk) {
            const float a0 = s_zp[kk][r0], a1 = s_zp[kk][r0 + 1];
            const float4 w0 = *(const float4*)&s_w[kk][c0];
            const float4 w1 = *(const float4*)&s_w[kk][c0 + 4];
            acc[0][0] += a0 * w0.x; acc[0][1] += a0 * w0.y; acc[0][2] += a0 * w0.z; acc[0][3] += a0 * w0.w;
            acc[0][4] += a0 * w1.x; acc[0][5] += a0 * w1.y; acc[0][6] += a0 * w1.z; acc[0][7] += a0 * w1.w;
            acc[1][0] += a1 * w0.x; acc[1][1] += a1 * w0.y; acc[1][2] += a1 * w0.z; acc[1][3] += a1 * w0.w;
            acc[1][4] += a1 * w1.x; acc[1][5] += a1 * w1.y; acc[1][6] += a1 * w1.z; acc[1][7] += a1 * w1.w;
        }
    }
#pragma unroll
    for (int j = 0; j < 8; ++j) {
        const float bv = bia[c0 + j];
        s_out[c0 + j][r0]     = fmaxf(acc[0][j] + bv, 0.f);
        s_out[c0 + j][r0 + 1] = fmaxf(acc[1][j] + bv, 0.f);
    }
}

// ------------------- decoder layer 3: 256 -> NOUT (3 or 9) -----------------
template<int NOUT>
__device__ __forceinline__ void dec_layer3(const float (*s_in)[TR + 1], float* __restrict__ xbase,
                                           const float* __restrict__ W2,
                                           const float* __restrict__ b2, int tid)
{
    if (tid < 16 * NOUT) {
        const int r = tid / NOUT, c = tid - r * NOUT;
        float acc = b2[c];
        const float* __restrict__ w = W2 + c * 256;
#pragma unroll 8
        for (int k = 0; k < 256; ++k) acc += s_in[k][r] * w[k];
        xbase[r * 12 + c] = acc;
    }
}

// ----------------------------- decoder kernel ------------------------------
__global__ void __launch_bounds__(NTHR, 2)
dec_kernel(const float* __restrict__ zin, float* __restrict__ xout,
           const float* __restrict__ dp_w0, const float* __restrict__ dp_b0,
           const float* __restrict__ dp_w1, const float* __restrict__ dp_b1,
           const float* __restrict__ dp_w2, const float* __restrict__ dp_b2,
           const float* __restrict__ dr_w0, const float* __restrict__ dr_b0,
           const float* __restrict__ dr_w1, const float* __restrict__ dr_b1,
           const float* __restrict__ dr_w2, const float* __restrict__ dr_b2)
{
    __shared__ __align__(16) float s_a[256][TR + 1];
    __shared__ __align__(16) float s_b[256][TR + 1];
    __shared__ __align__(16) float s_w[8][256];
    __shared__ __align__(16) float s_zp[8][TR + 1];
    const int tid = threadIdx.x;
    const size_t row0 = (size_t)blockIdx.x * TR;

    // pos: 32 -> 256 -> 256 -> 3
    dec_layer1<32>(zin, row0, 0, dp_w0, dp_b0, s_zp, s_w, s_a, tid);
    __syncthreads();
    layer_dense256(s_a, s_b, dp_w1, dp_b1, s_w, tid);
    __syncthreads();
    dec_layer3<3>(s_b, xout + row0 * 12, dp_w2, dp_b2, tid);
    __syncthreads();
    // rest: 96 -> 256 -> 256 -> 9
    dec_layer1<96>(zin, row0, 32, dr_w0, dr_b0, s_zp, s_w, s_a, tid);
    __syncthreads();
    layer_dense256(s_a, s_b, dr_w1, dr_b1, s_w, tid);
    __syncthreads();
    dec_layer3<9>(s_b, xout + row0 * 12 + 3, dr_w2, dr_b2, tid);
}

// --------------------------- Koopman recurrence ----------------------------
// 256 blocks x 32 rows, 512 threads. z ping-pong in LDS (transposed [k][r],
// stride 34), A staged in 32x128 panels from L2 each step. One kernel does
// all 64 steps; z_pred written directly.
__global__ void __launch_bounds__(512, 2)
koop_kernel(const float* __restrict__ zk, const float* __restrict__ u_seq,
            float* __restrict__ zpred,
            const float* __restrict__ A_w, const float* __restrict__ B_w)
{
    __shared__ __align__(16) float s_A[32][128];
    __shared__ __align__(16) float s_z[2][128][34];
    __shared__ __align__(16) float s_Bm[4][128];
    const int tid = threadIdx.x;
    const size_t row0 = (size_t)blockIdx.x * 32;

    if (tid < 128) {
        const float4 v = *(const float4*)(B_w + tid * 4);
        s_Bm[0][tid] = v.x; s_Bm[1][tid] = v.y; s_Bm[2][tid] = v.z; s_Bm[3][tid] = v.w;
    }
    {   // stage z0 transposed
        const int r = tid & 31, kg = tid >> 5;        // kg < 16
        const float* src = zk + (row0 + r) * 128 + kg * 8;
        const float4 v0 = *(const float4*)src;
        const float4 v1 = *(const float4*)(src + 4);
        const int k = kg * 8;
        s_z[0][k + 0][r] = v0.x; s_z[0][k + 1][r] = v0.y; s_z[0][k + 2][r] = v0.z; s_z[0][k + 3][r] = v0.w;
        s_z[0][k + 4][r] = v1.x; s_z[0][k + 5][r] = v1.y; s_z[0][k + 6][r] = v1.z; s_z[0][k + 7][r] = v1.w;
    }
    __syncthreads();

    const int cg = tid & 31, rg = tid >> 5;           // rg < 16
    const int c0 = cg * 4, r0 = rg * 2;
    const int pc = tid & 127, pk = (tid >> 7) * 8;    // A-panel staging ids
    float4 q0 = *(const float4*)(A_w + pc * 128 + pk);          // chunk 0
    float4 q1 = *(const float4*)(A_w + pc * 128 + pk + 4);

#pragma unroll 1
    for (int m = 0; m < 64; ++m) {
        const int p = m & 1;
        const float4 uv0 = *(const float4*)(u_seq + (row0 + r0) * 256 + m * 4);
        const float4 uv1 = *(const float4*)(u_seq + (row0 + r0 + 1) * 256 + m * 4);
        float acc[2][4];
#pragma unroll
        for (int j = 0; j < 4; ++j) {
            const int c = c0 + j;
            acc[0][j] = s_Bm[0][c] * uv0.x + s_Bm[1][c] * uv0.y + s_Bm[2][c] * uv0.z + s_Bm[3][c] * uv0.w;
            acc[1][j] = s_Bm[0][c] * uv1.x + s_Bm[1][c] * uv1.y + s_Bm[2][c] * uv1.z + s_Bm[3][c] * uv1.w;
        }
#pragma unroll 1
        for (int kc = 0; kc < 4; ++kc) {
            __syncthreads();
            s_A[pk + 0][pc] = q0.x; s_A[pk + 1][pc] = q0.y; s_A[pk + 2][pc] = q0.z; s_A[pk + 3][pc] = q0.w;
            s_A[pk + 4][pc] = q1.x; s_A[pk + 5][pc] = q1.y; s_A[pk + 6][pc] = q1.z; s_A[pk + 7][pc] = q1.w;
            {
                const int nk0 = ((kc + 1) & 3) * 32;  // next chunk (wraps to 0)
                q0 = *(const float4*)(A_w + pc * 128 + nk0 + pk);
                q1 = *(const float4*)(A_w + pc * 128 + nk0 + pk + 4);
            }
            __syncthreads();
#pragma unroll
            for (int kk = 0; kk < 32; ++kk) {
                const int k = kc * 32 + kk;
                const float a0 = s_z[p][k][r0], a1 = s_z[p][k][r0 + 1];
                const float4 w = *(const float4*)&s_A[kk][c0];
                acc[0][0] += a0 * w.x; acc[0][1] += a0 * w.y; acc[0][2] += a0 * w.z; acc[0][3] += a0 * w.w;
                acc[1][0] += a1 * w.x; acc[1][1] += a1 * w.y; acc[1][2] += a1 * w.z; acc[1][3] += a1 * w.w;
            }
        }
        float* orow0 = zpred + (row0 + r0) * 8192 + m * 128 + c0;
        float* orow1 = zpred + (row0 + r0 + 1) * 8192 + m * 128 + c0;
        *(float4*)orow0 = make_float4(acc[0][0], acc[0][1], acc[0][2], acc[0][3]);
        *(float4*)orow1 = make_float4(acc[1][0], acc[1][1], acc[1][2], acc[1][3]);
        const int pn = p ^ 1;
#pragma unroll
        for (int j = 0; j < 4; ++j) {
            s_z[pn][c0 + j][r0]     = acc[0][j];
            s_z[pn][c0 + j][r0 + 1] = acc[1][j];
        }
        // hazard vs next step covered by next kc=0 top barrier
    }
}

// ------------------------------- launcher ----------------------------------
extern "C" void kernel_launch(void* const* d_in, const int* in_sizes, int n_in,
                              void* d_out, int out_size, void* d_ws, size_t ws_size,
                              hipStream_t stream)
{
    (void)in_sizes; (void)n_in; (void)out_size; (void)ws_size;
    const float* x_k    = (const float*)d_in[0];
    const float* u_seq  = (const float*)d_in[1];
    const float* x_next = (const float*)d_in[2];
    const float* ep_w0 = (const float*)d_in[3];  const float* ep_b0 = (const float*)d_in[4];
    const float* ep_w1 = (const float*)d_in[5];  const float* ep_b1 = (const float*)d_in[6];
    const float* ep_w2 = (const float*)d_in[7];  const float* ep_b2 = (const float*)d_in[8];
    const float* er_w0 = (const float*)d_in[9];  const float* er_b0 = (const float*)d_in[10];
    const float* er_w1 = (const float*)d_in[11]; const float* er_b1 = (const float*)d_in[12];
    const float* er_w2 = (const float*)d_in[13]; const float* er_b2 = (const float*)d_in[14];
    const float* dp_w0 = (const float*)d_in[15]; const float* dp_b0 = (const float*)d_in[16];
    const float* dp_w1 = (const float*)d_in[17]; const float* dp_b1 = (const float*)d_in[18];
    const float* dp_w2 = (const float*)d_in[19]; const float* dp_b2 = (const float*)d_in[20];
    const float* dr_w0 = (const float*)d_in[21]; const float* dr_b0 = (const float*)d_in[22];
    const float* dr_w1 = (const float*)d_in[23]; const float* dr_b1 = (const float*)d_in[24];
    const float* dr_w2 = (const float*)d_in[25]; const float* dr_b2 = (const float*)d_in[26];
    const float* A_w   = (const float*)d_in[27];
    const float* B_w   = (const float*)d_in[28];

    float* out = (float*)d_out;
    float* o0 = out;              // x_k_hat          [8192,12]
    float* o1 = out + 98304;      // x_target_seq_hat [8192,64,12]
    float* o2 = out + 6389760;    // z_pred_seq       [8192,64,128]
    float* o3 = out + 73498624;   // x_pred_seq_hat   [8192,64,12]
    float* o4 = out + 79790080;   // z_target_seq     [8192,64,128]
    float* zkbuf = (float*)d_ws;  // z_k              [8192,128]

    // encode x_k -> z_k (workspace)
    enc_kernel<<<8192 / TR, NTHR, 0, stream>>>(x_k, zkbuf,
        ep_w0, ep_b0, ep_w1, ep_b1, ep_w2, ep_b2,
        er_w0, er_b0, er_w1, er_b1, er_w2, er_b2);
    // encode x_next_seq -> z_target_seq (output 4)
    enc_kernel<<<524288 / TR, NTHR, 0, stream>>>(x_next, o4,
        ep_w0, ep_b0, ep_w1, ep_b1, ep_w2, ep_b2,
        er_w0, er_b0, er_w1, er_b1, er_w2, er_b2);
    // Koopman scan -> z_pred_seq (output 2)
    koop_kernel<<<256, 512, 0, stream>>>(zkbuf, u_seq, o2, A_w, B_w);
    // decode z_k -> x_k_hat (output 0)
    dec_kernel<<<8192 / TR, NTHR, 0, stream>>>(zkbuf, o0,
        dp_w0, dp_b0, dp_w1, dp_b1, dp_w2, dp_b2,
        dr_w0, dr_b0, dr_w1, dr_b1, dr_w2, dr_b2);
    // decode z_target_seq -> x_target_seq_hat (output 1)
    dec_kernel<<<524288 / TR, NTHR, 0, stream>>>(o4, o1,
        dp_w0, dp_b0, dp_w1, dp_b1, dp_w2, dp_b2,
        dr_w0, dr_b0, dr_w1, dr_b1, dr_w2, dr_b2);
    // decode z_pred_seq -> x_pred_seq_hat (output 3)
    dec_kernel<<<524288 / TR, NTHR, 0, stream>>>(o2, o3,
        dp_w0, dp_b0, dp_w1, dp_b1, dp_w2, dp_b2,
        dr_w0, dr_b0, dr_w1, dr_b1, dr_w2, dr_b2);
}

// Round 3
// 9091.763 us; speedup vs baseline: 1.4888x; 1.4888x over previous
//
#include <hip/hip_runtime.h>
#include <cstddef>

// ---------------------------------------------------------------------------
// DeepKoopmanSplit — fp32, fused per-MLP kernels. Round 2 (resubmit; infra).
// B=8192, M=64, H=256, LP=32, LR=96, L=128, CD=4.
// TR=32 rows/block, 4 rows x 8 cols per thread in dense layers.
// Weight LDS reads are 16B-lane-stride float4 (conflict-free); s_w double-
// buffered (1 barrier per k-chunk); dense runs in-place on one activation
// buffer (LDS 51.7KB -> 3 blocks/CU).
// ---------------------------------------------------------------------------

#define TR   32
#define NTHR 256

// ------------------------- encoder layer 1 (K=3 or 9) ----------------------
template<int KIN, int OFF>
__device__ __forceinline__ void enc_layer1(const float (*s_x)[12], float (*s_h)[TR + 1],
                                           const float* __restrict__ W,
                                           const float* __restrict__ bia, int tid)
{
    const int r = tid & 31, cgp = tid >> 5;          // 32 rows x 8 col-groups
    float xv[KIN];
#pragma unroll
    for (int t = 0; t < KIN; ++t) xv[t] = s_x[r][OFF + t];
#pragma unroll 4
    for (int j = 0; j < 32; ++j) {
        const int c = cgp * 32 + j;
        float acc = bia[c];
#pragma unroll
        for (int t = 0; t < KIN; ++t) acc += W[c * KIN + t] * xv[t];
        s_h[c][r] = fmaxf(acc, 0.f);                 // lanes r consecutive: no conflict
    }
    __syncthreads();
}

// ------------------- dense 256->256 + ReLU (the heavy layer) ---------------
// s_in/s_out transposed [k][r], stride 33. Per thread: 4 rows x 8 cols, cols
// at 4*cg and 128+4*cg so the float4 weight reads are 16B lane-stride
// (conflict-free). s_w double-buffered: ONE barrier per k-chunk.
// In-place safe: post-loop barrier before the writeback.
__device__ __forceinline__ void layer_dense256(const float (*s_in)[TR + 1], float (*s_out)[TR + 1],
                                               const float* __restrict__ W,
                                               const float* __restrict__ bia,
                                               float (*s_w)[8][256], int tid)
{
    const int cg = tid & 31, rg = tid >> 5;          // 32 col-grps x 8 row-grps
    const int c0 = cg * 4, c1 = 128 + cg * 4, r0 = rg * 4;
    float acc[4][8];
#pragma unroll
    for (int i = 0; i < 4; ++i)
#pragma unroll
        for (int j = 0; j < 8; ++j) acc[i][j] = 0.f;

    const float* wrow = W + tid * 256;               // thread stages row c=tid
    float4 p0 = *(const float4*)(wrow);
    float4 p1 = *(const float4*)(wrow + 4);
#pragma unroll 1
    for (int kc = 0; kc < 32; ++kc) {
        float (*w)[256] = s_w[kc & 1];
        w[0][tid] = p0.x; w[1][tid] = p0.y; w[2][tid] = p0.z; w[3][tid] = p0.w;
        w[4][tid] = p1.x; w[5][tid] = p1.y; w[6][tid] = p1.z; w[7][tid] = p1.w;
        if (kc < 31) {
            p0 = *(const float4*)(wrow + (kc + 1) * 8);
            p1 = *(const float4*)(wrow + (kc + 1) * 8 + 4);
        }
        __syncthreads();                              // single barrier per chunk
#pragma unroll
        for (int kk = 0; kk < 8; ++kk) {
            const int k = kc * 8 + kk;
            const float a0 = s_in[k][r0],     a1 = s_in[k][r0 + 1];
            const float a2 = s_in[k][r0 + 2], a3 = s_in[k][r0 + 3];
            const float4 w0 = *(const float4*)&w[kk][c0];
            const float4 w1 = *(const float4*)&w[kk][c1];
            acc[0][0] += a0 * w0.x; acc[0][1] += a0 * w0.y; acc[0][2] += a0 * w0.z; acc[0][3] += a0 * w0.w;
            acc[0][4] += a0 * w1.x; acc[0][5] += a0 * w1.y; acc[0][6] += a0 * w1.z; acc[0][7] += a0 * w1.w;
            acc[1][0] += a1 * w0.x; acc[1][1] += a1 * w0.y; acc[1][2] += a1 * w0.z; acc[1][3] += a1 * w0.w;
            acc[1][4] += a1 * w1.x; acc[1][5] += a1 * w1.y; acc[1][6] += a1 * w1.z; acc[1][7] += a1 * w1.w;
            acc[2][0] += a2 * w0.x; acc[2][1] += a2 * w0.y; acc[2][2] += a2 * w0.z; acc[2][3] += a2 * w0.w;
            acc[2][4] += a2 * w1.x; acc[2][5] += a2 * w1.y; acc[2][6] += a2 * w1.z; acc[2][7] += a2 * w1.w;
            acc[3][0] += a3 * w0.x; acc[3][1] += a3 * w0.y; acc[3][2] += a3 * w0.z; acc[3][3] += a3 * w0.w;
            acc[3][4] += a3 * w1.x; acc[3][5] += a3 * w1.y; acc[3][6] += a3 * w1.z; acc[3][7] += a3 * w1.w;
        }
    }
    __syncthreads();                                  // all s_in reads done -> in-place OK
#pragma unroll
    for (int j = 0; j < 4; ++j) {
        const float b0 = bia[c0 + j], b1 = bia[c1 + j];
#pragma unroll
        for (int i = 0; i < 4; ++i) {
            s_out[c0 + j][r0 + i] = fmaxf(acc[i][j] + b0, 0.f);
            s_out[c1 + j][r0 + i] = fmaxf(acc[i][j + 4] + b1, 0.f);
        }
    }
}

// -------------------- encoder layer 3: 256 -> N3 (32 or 96) ----------------
template<int N3>
__device__ __forceinline__ void enc_layer3(const float (*s_in)[TR + 1], float* __restrict__ zbase,
                                           const float* __restrict__ W2,
                                           const float* __restrict__ b2,
                                           float (*s_w)[8][256], int tid)
{
    constexpr int CT = N3 / 32;
    constexpr int PR = (N3 * 8) / 256;               // 1 (pos) or 3 (rest)
    const int cg = tid & 31, rg = tid >> 5;
    const int r0 = rg * 4;
    float acc[4][CT];
#pragma unroll
    for (int i = 0; i < 4; ++i)
#pragma unroll
        for (int j = 0; j < CT; ++j) acc[i][j] = 0.f;

    float pr[PR];
#pragma unroll
    for (int u = 0; u < PR; ++u) {
        const int idx = u * 256 + tid;
        pr[u] = W2[(idx % N3) * 256 + (idx / N3)];
    }
#pragma unroll 1
    for (int kc = 0; kc < 32; ++kc) {
        float (*w)[256] = s_w[kc & 1];
#pragma unroll
        for (int u = 0; u < PR; ++u) {
            const int idx = u * 256 + tid;
            w[idx / N3][idx % N3] = pr[u];
        }
        if (kc < 31) {
#pragma unroll
            for (int u = 0; u < PR; ++u) {
                const int idx = u * 256 + tid;
                pr[u] = W2[(idx % N3) * 256 + (kc + 1) * 8 + (idx / N3)];
            }
        }
        __syncthreads();
#pragma unroll
        for (int kk = 0; kk < 8; ++kk) {
            const int k = kc * 8 + kk;
            const float a0 = s_in[k][r0],     a1 = s_in[k][r0 + 1];
            const float a2 = s_in[k][r0 + 2], a3 = s_in[k][r0 + 3];
#pragma unroll
            for (int j = 0; j < CT; ++j) {
                const float wv = w[kk][cg + 32 * j];
                acc[0][j] += a0 * wv;
                acc[1][j] += a1 * wv;
                acc[2][j] += a2 * wv;
                acc[3][j] += a3 * wv;
            }
        }
    }
#pragma unroll
    for (int j = 0; j < CT; ++j) {
        const int c = cg + 32 * j;
        const float bv = b2[c];
#pragma unroll
        for (int i = 0; i < 4; ++i)
            zbase[(size_t)(r0 + i) * 128 + c] = acc[i][j] + bv;
    }
}

// ----------------------------- encoder kernel ------------------------------
__global__ void __launch_bounds__(NTHR, 3)
enc_kernel(const float* __restrict__ xin, float* __restrict__ zout,
           const float* __restrict__ ep_w0, const float* __restrict__ ep_b0,
           const float* __restrict__ ep_w1, const float* __restrict__ ep_b1,
           const float* __restrict__ ep_w2, const float* __restrict__ ep_b2,
           const float* __restrict__ er_w0, const float* __restrict__ er_b0,
           const float* __restrict__ er_w1, const float* __restrict__ er_b1,
           const float* __restrict__ er_w2, const float* __restrict__ er_b2)
{
    __shared__ __align__(16) float s_x[TR][12];
    __shared__ __align__(16) float s_a[256][TR + 1];
    __shared__ __align__(16) float s_w[2][8][256];
    const int tid = threadIdx.x;
    const size_t row0 = (size_t)blockIdx.x * TR;

    for (int idx = tid; idx < TR * 12; idx += NTHR)
        ((float*)s_x)[idx] = xin[row0 * 12 + idx];
    __syncthreads();

    // pos net: 3 -> 256 -> 256 -> 32
    enc_layer1<3, 0>(s_x, s_a, ep_w0, ep_b0, tid);
    layer_dense256(s_a, s_a, ep_w1, ep_b1, s_w, tid);
    __syncthreads();
    enc_layer3<32>(s_a, zout + row0 * 128, ep_w2, ep_b2, s_w, tid);
    __syncthreads();
    // rest net: 9 -> 256 -> 256 -> 96
    enc_layer1<9, 3>(s_x, s_a, er_w0, er_b0, tid);
    layer_dense256(s_a, s_a, er_w1, er_b1, s_w, tid);
    __syncthreads();
    enc_layer3<96>(s_a, zout + row0 * 128 + 32, er_w2, er_b2, s_w, tid);
}

// ---------------- decoder layer 1: K=32 (pos) or 96 (rest) -----------------
template<int KLEN>
__device__ __forceinline__ void dec_layer1(const float* __restrict__ zin, size_t row0, int koff,
                                           const float* __restrict__ W,
                                           const float* __restrict__ bia,
                                           float (*s_zp)[8][TR + 1], float (*s_w)[8][256],
                                           float (*s_out)[TR + 1], int tid)
{
    constexpr int CH = KLEN / 8;
    const int cg = tid & 31, rg = tid >> 5;
    const int c0 = cg * 4, c1 = 128 + cg * 4, r0 = rg * 4;
    float acc[4][8];
#pragma unroll
    for (int i = 0; i < 4; ++i)
#pragma unroll
        for (int j = 0; j < 8; ++j) acc[i][j] = 0.f;

    const float* wrow = W + tid * KLEN;
    float4 p0 = *(const float4*)(wrow);
    float4 p1 = *(const float4*)(wrow + 4);
    const int zr = tid & 31, zkk = tid >> 5;          // all 256 threads stage z
    float zv = zin[(row0 + zr) * 128 + koff + zkk];
#pragma unroll 1
    for (int kc = 0; kc < CH; ++kc) {
        const int b = kc & 1;
        float (*w)[256] = s_w[b];
        w[0][tid] = p0.x; w[1][tid] = p0.y; w[2][tid] = p0.z; w[3][tid] = p0.w;
        w[4][tid] = p1.x; w[5][tid] = p1.y; w[6][tid] = p1.z; w[7][tid] = p1.w;
        s_zp[b][zkk][zr] = zv;
        if (kc < CH - 1) {
            p0 = *(const float4*)(wrow + (kc + 1) * 8);
            p1 = *(const float4*)(wrow + (kc + 1) * 8 + 4);
            zv = zin[(row0 + zr) * 128 + koff + (kc + 1) * 8 + zkk];
        }
        __syncthreads();
#pragma unroll
        for (int kk = 0; kk < 8; ++kk) {
            const float a0 = s_zp[b][kk][r0],     a1 = s_zp[b][kk][r0 + 1];
            const float a2 = s_zp[b][kk][r0 + 2], a3 = s_zp[b][kk][r0 + 3];
            const float4 w0 = *(const float4*)&w[kk][c0];
            const float4 w1 = *(const float4*)&w[kk][c1];
            acc[0][0] += a0 * w0.x; acc[0][1] += a0 * w0.y; acc[0][2] += a0 * w0.z; acc[0][3] += a0 * w0.w;
            acc[0][4] += a0 * w1.x; acc[0][5] += a0 * w1.y; acc[0][6] += a0 * w1.z; acc[0][7] += a0 * w1.w;
            acc[1][0] += a1 * w0.x; acc[1][1] += a1 * w0.y; acc[1][2] += a1 * w0.z; acc[1][3] += a1 * w0.w;
            acc[1][4] += a1 * w1.x; acc[1][5] += a1 * w1.y; acc[1][6] += a1 * w1.z; acc[1][7] += a1 * w1.w;
            acc[2][0] += a2 * w0.x; acc[2][1] += a2 * w0.y; acc[2][2] += a2 * w0.z; acc[2][3] += a2 * w0.w;
            acc[2][4] += a2 * w1.x; acc[2][5] += a2 * w1.y; acc[2][6] += a2 * w1.z; acc[2][7] += a2 * w1.w;
            acc[3][0] += a3 * w0.x; acc[3][1] += a3 * w0.y; acc[3][2] += a3 * w0.z; acc[3][3] += a3 * w0.w;
            acc[3][4] += a3 * w1.x; acc[3][5] += a3 * w1.y; acc[3][6] += a3 * w1.z; acc[3][7] += a3 * w1.w;
        }
    }
    // s_out is a different LDS array than s_zp/s_w: safe to write without a barrier
#pragma unroll
    for (int j = 0; j < 4; ++j) {
        const float b0 = bia[c0 + j], b1 = bia[c1 + j];
#pragma unroll
        for (int i = 0; i < 4; ++i) {
            s_out[c0 + j][r0 + i] = fmaxf(acc[i][j] + b0, 0.f);
            s_out[c1 + j][r0 + i] = fmaxf(acc[i][j + 4] + b1, 0.f);
        }
    }
}

// ------------------- decoder layer 3: 256 -> NOUT (3 or 9) -----------------
template<int NOUT>
__device__ __forceinline__ void dec_layer3(const float (*s_in)[TR + 1], float* __restrict__ xbase,
                                           const float* __restrict__ W2,
                                           const float* __restrict__ b2, int tid)
{
    for (int o = tid; o < TR * NOUT; o += NTHR) {
        const int r = o / NOUT, c = o - (o / NOUT) * NOUT;
        float acc = b2[c];
        const float* __restrict__ w = W2 + c * 256;
#pragma unroll 8
        for (int k = 0; k < 256; ++k) acc += s_in[k][r] * w[k];
        xbase[r * 12 + c] = acc;
    }
}

// ----------------------------- decoder kernel ------------------------------
__global__ void __launch_bounds__(NTHR, 3)
dec_kernel(const float* __restrict__ zin, float* __restrict__ xout,
           const float* __restrict__ dp_w0, const float* __restrict__ dp_b0,
           const float* __restrict__ dp_w1, const float* __restrict__ dp_b1,
           const float* __restrict__ dp_w2, const float* __restrict__ dp_b2,
           const float* __restrict__ dr_w0, const float* __restrict__ dr_b0,
           const float* __restrict__ dr_w1, const float* __restrict__ dr_b1,
           const float* __restrict__ dr_w2, const float* __restrict__ dr_b2)
{
    __shared__ __align__(16) float s_a[256][TR + 1];
    __shared__ __align__(16) float s_w[2][8][256];
    __shared__ __align__(16) float s_zp[2][8][TR + 1];
    const int tid = threadIdx.x;
    const size_t row0 = (size_t)blockIdx.x * TR;

    // pos: 32 -> 256 -> 256 -> 3
    dec_layer1<32>(zin, row0, 0, dp_w0, dp_b0, s_zp, s_w, s_a, tid);
    __syncthreads();
    layer_dense256(s_a, s_a, dp_w1, dp_b1, s_w, tid);
    __syncthreads();
    dec_layer3<3>(s_a, xout + row0 * 12, dp_w2, dp_b2, tid);
    __syncthreads();
    // rest: 96 -> 256 -> 256 -> 9
    dec_layer1<96>(zin, row0, 32, dr_w0, dr_b0, s_zp, s_w, s_a, tid);
    __syncthreads();
    layer_dense256(s_a, s_a, dr_w1, dr_b1, s_w, tid);
    __syncthreads();
    dec_layer3<9>(s_a, xout + row0 * 12 + 3, dr_w2, dr_b2, tid);
}

// --------------------------- Koopman recurrence ----------------------------
// Unchanged from baseline (not in the top-5 dispatches).
__global__ void __launch_bounds__(512, 2)
koop_kernel(const float* __restrict__ zk, const float* __restrict__ u_seq,
            float* __restrict__ zpred,
            const float* __restrict__ A_w, const float* __restrict__ B_w)
{
    __shared__ __align__(16) float s_A[32][128];
    __shared__ __align__(16) float s_z[2][128][34];
    __shared__ __align__(16) float s_Bm[4][128];
    const int tid = threadIdx.x;
    const size_t row0 = (size_t)blockIdx.x * 32;

    if (tid < 128) {
        const float4 v = *(const float4*)(B_w + tid * 4);
        s_Bm[0][tid] = v.x; s_Bm[1][tid] = v.y; s_Bm[2][tid] = v.z; s_Bm[3][tid] = v.w;
    }
    {   // stage z0 transposed
        const int r = tid & 31, kg = tid >> 5;        // kg < 16
        const float* src = zk + (row0 + r) * 128 + kg * 8;
        const float4 v0 = *(const float4*)src;
        const float4 v1 = *(const float4*)(src + 4);
        const int k = kg * 8;
        s_z[0][k + 0][r] = v0.x; s_z[0][k + 1][r] = v0.y; s_z[0][k + 2][r] = v0.z; s_z[0][k + 3][r] = v0.w;
        s_z[0][k + 4][r] = v1.x; s_z[0][k + 5][r] = v1.y; s_z[0][k + 6][r] = v1.z; s_z[0][k + 7][r] = v1.w;
    }
    __syncthreads();

    const int cg = tid & 31, rg = tid >> 5;           // rg < 16
    const int c0 = cg * 4, r0 = rg * 2;
    const int pc = tid & 127, pk = (tid >> 7) * 8;    // A-panel staging ids
    float4 q0 = *(const float4*)(A_w + pc * 128 + pk);          // chunk 0
    float4 q1 = *(const float4*)(A_w + pc * 128 + pk + 4);

#pragma unroll 1
    for (int m = 0; m < 64; ++m) {
        const int p = m & 1;
        const float4 uv0 = *(const float4*)(u_seq + (row0 + r0) * 256 + m * 4);
        const float4 uv1 = *(const float4*)(u_seq + (row0 + r0 + 1) * 256 + m * 4);
        float acc[2][4];
#pragma unroll
        for (int j = 0; j < 4; ++j) {
            const int c = c0 + j;
            acc[0][j] = s_Bm[0][c] * uv0.x + s_Bm[1][c] * uv0.y + s_Bm[2][c] * uv0.z + s_Bm[3][c] * uv0.w;
            acc[1][j] = s_Bm[0][c] * uv1.x + s_Bm[1][c] * uv1.y + s_Bm[2][c] * uv1.z + s_Bm[3][c] * uv1.w;
        }
#pragma unroll 1
        for (int kc = 0; kc < 4; ++kc) {
            __syncthreads();
            s_A[pk + 0][pc] = q0.x; s_A[pk + 1][pc] = q0.y; s_A[pk + 2][pc] = q0.z; s_A[pk + 3][pc] = q0.w;
            s_A[pk + 4][pc] = q1.x; s_A[pk + 5][pc] = q1.y; s_A[pk + 6][pc] = q1.z; s_A[pk + 7][pc] = q1.w;
            {
                const int nk0 = ((kc + 1) & 3) * 32;  // next chunk (wraps to 0)
                q0 = *(const float4*)(A_w + pc * 128 + nk0 + pk);
                q1 = *(const float4*)(A_w + pc * 128 + nk0 + pk + 4);
            }
            __syncthreads();
#pragma unroll
            for (int kk = 0; kk < 32; ++kk) {
                const int k = kc * 32 + kk;
                const float a0 = s_z[p][k][r0], a1 = s_z[p][k][r0 + 1];
                const float4 w = *(const float4*)&s_A[kk][c0];
                acc[0][0] += a0 * w.x; acc[0][1] += a0 * w.y; acc[0][2] += a0 * w.z; acc[0][3] += a0 * w.w;
                acc[1][0] += a1 * w.x; acc[1][1] += a1 * w.y; acc[1][2] += a1 * w.z; acc[1][3] += a1 * w.w;
            }
        }
        float* orow0 = zpred + (row0 + r0) * 8192 + m * 128 + c0;
        float* orow1 = zpred + (row0 + r0 + 1) * 8192 + m * 128 + c0;
        *(float4*)orow0 = make_float4(acc[0][0], acc[0][1], acc[0][2], acc[0][3]);
        *(float4*)orow1 = make_float4(acc[1][0], acc[1][1], acc[1][2], acc[1][3]);
        const int pn = p ^ 1;
#pragma unroll
        for (int j = 0; j < 4; ++j) {
            s_z[pn][c0 + j][r0]     = acc[0][j];
            s_z[pn][c0 + j][r0 + 1] = acc[1][j];
        }
        // hazard vs next step covered by next kc=0 top barrier
    }
}

// ------------------------------- launcher ----------------------------------
extern "C" void kernel_launch(void* const* d_in, const int* in_sizes, int n_in,
                              void* d_out, int out_size, void* d_ws, size_t ws_size,
                              hipStream_t stream)
{
    (void)in_sizes; (void)n_in; (void)out_size; (void)ws_size;
    const float* x_k    = (const float*)d_in[0];
    const float* u_seq  = (const float*)d_in[1];
    const float* x_next = (const float*)d_in[2];
    const float* ep_w0 = (const float*)d_in[3];  const float* ep_b0 = (const float*)d_in[4];
    const float* ep_w1 = (const float*)d_in[5];  const float* ep_b1 = (const float*)d_in[6];
    const float* ep_w2 = (const float*)d_in[7];  const float* ep_b2 = (const float*)d_in[8];
    const float* er_w0 = (const float*)d_in[9];  const float* er_b0 = (const float*)d_in[10];
    const float* er_w1 = (const float*)d_in[11]; const float* er_b1 = (const float*)d_in[12];
    const float* er_w2 = (const float*)d_in[13]; const float* er_b2 = (const float*)d_in[14];
    const float* dp_w0 = (const float*)d_in[15]; const float* dp_b0 = (const float*)d_in[16];
    const float* dp_w1 = (const float*)d_in[17]; const float* dp_b1 = (const float*)d_in[18];
    const float* dp_w2 = (const float*)d_in[19]; const float* dp_b2 = (const float*)d_in[20];
    const float* dr_w0 = (const float*)d_in[21]; const float* dr_b0 = (const float*)d_in[22];
    const float* dr_w1 = (const float*)d_in[23]; const float* dr_b1 = (const float*)d_in[24];
    const float* dr_w2 = (const float*)d_in[25]; const float* dr_b2 = (const float*)d_in[26];
    const float* A_w   = (const float*)d_in[27];
    const float* B_w   = (const float*)d_in[28];

    float* out = (float*)d_out;
    float* o0 = out;              // x_k_hat          [8192,12]
    float* o1 = out + 98304;      // x_target_seq_hat [8192,64,12]
    float* o2 = out + 6389760;    // z_pred_seq       [8192,64,128]
    float* o3 = out + 73498624;   // x_pred_seq_hat   [8192,64,12]
    float* o4 = out + 79790080;   // z_target_seq     [8192,64,128]
    float* zkbuf = (float*)d_ws;  // z_k              [8192,128]

    // encode x_k -> z_k (workspace)
    enc_kernel<<<8192 / TR, NTHR, 0, stream>>>(x_k, zkbuf,
        ep_w0, ep_b0, ep_w1, ep_b1, ep_w2, ep_b2,
        er_w0, er_b0, er_w1, er_b1, er_w2, er_b2);
    // encode x_next_seq -> z_target_seq (output 4)
    enc_kernel<<<524288 / TR, NTHR, 0, stream>>>(x_next, o4,
        ep_w0, ep_b0, ep_w1, ep_b1, ep_w2, ep_b2,
        er_w0, er_b0, er_w1, er_b1, er_w2, er_b2);
    // Koopman scan -> z_pred_seq (output 2)
    koop_kernel<<<256, 512, 0, stream>>>(zkbuf, u_seq, o2, A_w, B_w);
    // decode z_k -> x_k_hat (output 0)
    dec_kernel<<<8192 / TR, NTHR, 0, stream>>>(zkbuf, o0,
        dp_w0, dp_b0, dp_w1, dp_b1, dp_w2, dp_b2,
        dr_w0, dr_b0, dr_w1, dr_b1, dr_w2, dr_b2);
    // decode z_target_seq -> x_target_seq_hat (output 1)
    dec_kernel<<<524288 / TR, NTHR, 0, stream>>>(o4, o1,
        dp_w0, dp_b0, dp_w1, dp_b1, dp_w2, dp_b2,
        dr_w0, dr_b0, dr_w1, dr_b1, dr_w2, dr_b2);
    // decode z_pred_seq -> x_pred_seq_hat (output 3)
    dec_kernel<<<524288 / TR, NTHR, 0, stream>>>(o2, o3,
        dp_w0, dp_b0, dp_w1, dp_b1, dp_w2, dp_b2,
        dr_w0, dr_b0, dr_w1, dr_b1, dr_w2, dr_b2);
}